// Round 3
// baseline (2548.277 us; speedup 1.0000x reference)
//
#include <hip/hip_runtime.h>

#define KS 3
#define NN 65536
#define EE 524288
#define BB 64

typedef unsigned short u16;
typedef unsigned int u32;

__device__ __forceinline__ float bf2f(u16 u) {
  union { u32 i; float f; } v; v.i = ((u32)u) << 16; return v.f;
}
__device__ __forceinline__ u16 f2bf(float f) {
  union { float f; u32 i; } v; v.f = f;
  u32 x = v.i;
  x += 0x7fffu + ((x >> 16) & 1u);   // RNE
  return (u16)(x >> 16);
}

// ---------------- ws byte offsets (total ~94.8 MB) ----------------
static const size_t O_XBF   = 0;                      // N*16 bf16
static const size_t O_COEFF = 2097152;                // E*9 f32
static const size_t O_DEG   = O_COEFF + 18874368;     // N i32
static const size_t O_HBUF  = O_DEG + 262144;         // 64*128 f32 (memset with DEG)
static const size_t O_ROWS  = O_HBUF + 32768;         // (N+1) i32 padded
static const size_t O_CURS  = O_ROWS + 262400;        // N i32
static const size_t O_BSUM  = O_CURS + 262144;        // 256 i32 padded
static const size_t O_CSR   = O_BSUM + 1024;          // E i32
static const size_t O_H1    = O_CSR + 2097152;        // N*32 bf16
static const size_t O_H2    = O_H1 + 4194304;         // N*64 bf16
static const size_t O_H3    = O_H2 + 8388608;         // N*64 bf16
static const size_t O_D0    = O_H3 + 8388608;         // N*64 bf16
static const size_t O_D1    = O_D0 + 8388608;         // N*32 bf16
static const size_t O_ACC   = O_D1 + 4194304;         // N*64 f32
static const size_t O_XW    = O_ACC + 16777216;       // N*3*64 bf16
// end = O_XW + 25165824 = 99,386,624 bytes

// ---------------- x f32 -> bf16 ----------------
__global__ void cvt_x(const float* __restrict__ x, u16* __restrict__ xb) {
  int i = blockIdx.x * 256 + threadIdx.x;   // N*16 / 256 blocks
  xb[i] = f2bf(x[i]);
}

// ---------------- per-edge spline coefficients (f32) + degree histogram ----------------
__global__ void edge_prep(const float* __restrict__ pos, const int* __restrict__ ei,
                          float* __restrict__ coeff, int* __restrict__ deg) {
  int e = blockIdx.x * 256 + threadIdx.x;
  float2 p = ((const float2*)pos)[e];
  float fl0 = floorf(p.x), fl1 = floorf(p.y);
  float f0 = p.x - fl0, f1 = p.y - fl1;
  int b0 = (int)fl0, b1 = (int)fl1;
  float w0[3] = { 0.5f*(1.f-f0)*(1.f-f0), -f0*f0+f0+0.5f, 0.5f*f0*f0 };
  float w1[3] = { 0.5f*(1.f-f1)*(1.f-f1), -f1*f1+f1+0.5f, 0.5f*f1*f1 };
  int i0[3], i1[3];
#pragma unroll
  for (int s = 0; s < 3; ++s) {
    i0[s] = min(max(b0 + s, 0), KS - 1);
    i1[s] = min(max(b1 + s, 0), KS - 1);
  }
  float c[9] = {0,0,0,0,0,0,0,0,0};
#pragma unroll
  for (int s0 = 0; s0 < 3; ++s0)
#pragma unroll
    for (int s1 = 0; s1 < 3; ++s1)
      c[i0[s0] + KS * i1[s1]] += w0[s0] * w1[s1];
#pragma unroll
  for (int j = 0; j < 9; ++j) coeff[(size_t)e * 9 + j] = c[j];
  int d = ei[EE + e]; d = min(max(d, 0), NN - 1);
  atomicAdd(&deg[d], 1);
}

// ---------------- scans over deg[N], N = 256*256 ----------------
__global__ void scan1(const int* __restrict__ deg, int* __restrict__ rows,
                      int* __restrict__ bsum) {
  __shared__ int s[256];
  int t = threadIdx.x, b = blockIdx.x, i = b * 256 + t;
  int v = deg[i];
  s[t] = v; __syncthreads();
  for (int off = 1; off < 256; off <<= 1) {
    int x = (t >= off) ? s[t - off] : 0; __syncthreads();
    s[t] += x; __syncthreads();
  }
  rows[i] = s[t] - v;
  if (t == 255) bsum[b] = s[255];
}
__global__ void scan2(int* __restrict__ bsum) {
  __shared__ int s[256];
  int t = threadIdx.x;
  int v = bsum[t];
  s[t] = v; __syncthreads();
  for (int off = 1; off < 256; off <<= 1) {
    int x = (t >= off) ? s[t - off] : 0; __syncthreads();
    s[t] += x; __syncthreads();
  }
  bsum[t] = s[t] - v;
}
__global__ void scan3(int* __restrict__ rows, const int* __restrict__ bsum,
                      int* __restrict__ cursor) {
  int t = threadIdx.x, b = blockIdx.x, i = b * 256 + t;
  int v = rows[i] + bsum[b];
  rows[i] = v;
  cursor[i] = v;
  if (i == NN - 1) rows[NN] = EE;
}
__global__ void edge_fill(const int* __restrict__ ei, int* __restrict__ cursor,
                          int* __restrict__ csr) {
  int e = blockIdx.x * 256 + threadIdx.x;
  int d = ei[EE + e]; d = min(max(d, 0), NN - 1);
  int slot = atomicAdd(&cursor[d], 1);
  slot = min(max(slot, 0), EE - 1);
  csr[slot] = e;
}

// ---------------- xW[n,kk,o] = sum_i feat[n,i] * W[kbase+kk][i,o] ----------------
__global__ void gemm_xw(const u16* __restrict__ featA, const u16* __restrict__ featB,
                        int inA, int inB, const float* __restrict__ Wf,
                        u16* __restrict__ xW, int out) {
  extern __shared__ float lds[];
  const int in = inA + inB;
  const int tid = threadIdx.x;
  const int R = 256 / out;
  const int NODES = R * 4;
  const int kk = blockIdx.y;
  const int n0 = blockIdx.x * NODES;
  float* Wk = lds;                       // in*out
  float* F  = lds + (size_t)in * out;    // NODES*in

  for (int idx = tid; idx < in * out; idx += 256)
    Wk[idx] = Wf[(size_t)kk * in * out + idx];
  const int hA = inA >> 1, hB = inB >> 1, h = in >> 1;
  for (int idx = tid; idx < NODES * h; idx += 256) {
    int node = idx / h, p = idx - node * h;
    int n = n0 + node;
    u32 w = (p < hA) ? ((const u32*)featA)[(size_t)n * hA + p]
                     : ((const u32*)featB)[(size_t)n * hB + (p - hA)];
    F[node * in + 2 * p]     = bf2f((u16)(w & 0xffffu));
    F[node * in + 2 * p + 1] = bf2f((u16)(w >> 16));
  }
  __syncthreads();

  const int o = tid % out;
  const int r = tid / out;
  float acc0 = 0.f, acc1 = 0.f, acc2 = 0.f, acc3 = 0.f;
  const int nb = r * 4;
  for (int i = 0; i < in; i += 4) {
    float w0 = Wk[i * out + o];
    float w1 = Wk[(i + 1) * out + o];
    float w2 = Wk[(i + 2) * out + o];
    float w3 = Wk[(i + 3) * out + o];
    float4 fa = *(const float4*)&F[(nb + 0) * in + i];
    float4 fb = *(const float4*)&F[(nb + 1) * in + i];
    float4 fc = *(const float4*)&F[(nb + 2) * in + i];
    float4 fd = *(const float4*)&F[(nb + 3) * in + i];
    acc0 = fmaf(fa.x, w0, fmaf(fa.y, w1, fmaf(fa.z, w2, fmaf(fa.w, w3, acc0))));
    acc1 = fmaf(fb.x, w0, fmaf(fb.y, w1, fmaf(fb.z, w2, fmaf(fb.w, w3, acc1))));
    acc2 = fmaf(fc.x, w0, fmaf(fc.y, w1, fmaf(fc.z, w2, fmaf(fc.w, w3, acc2))));
    acc3 = fmaf(fd.x, w0, fmaf(fd.y, w1, fmaf(fd.z, w2, fmaf(fd.w, w3, acc3))));
  }
  size_t b0 = ((size_t)(n0 + nb) * 3 + kk) * out + o;
  size_t stride = (size_t)3 * out;
  xW[b0]              = f2bf(acc0);
  xW[b0 + stride]     = f2bf(acc1);
  xW[b0 + 2 * stride] = f2bf(acc2);
  xW[b0 + 3 * stride] = f2bf(acc3);
}

// ---------------- per-node 3-tap aggregate pass ----------------
template <int OUT, bool INIT>
__global__ void aggregate_g(const u16* __restrict__ xW, const float* __restrict__ coeff,
                            const int* __restrict__ ei, const int* __restrict__ csr,
                            const int* __restrict__ rows, int kb,
                            float* __restrict__ acc) {
  const int tid = threadIdx.x;
  const int NPB = 64 / OUT;
  const int n = blockIdx.x * NPB + tid / OUT;
  const int o = tid % OUT;
  const int rs = rows[n], re = rows[n + 1];
  float a = 0.f;
  for (int r = rs; r < re; ++r) {
    int e = csr[r]; e = min(max(e, 0), EE - 1);
    int s = ei[e];  s = min(max(s, 0), NN - 1);
    const float* cf = coeff + (size_t)e * 9 + kb;
    const u16* p  = xW + (size_t)s * 3 * OUT + o;
    a += cf[0] * bf2f(p[0])
       + cf[1] * bf2f(p[OUT])
       + cf[2] * bf2f(p[2 * OUT]);
  }
  if (INIT) acc[(size_t)n * OUT + o] = a;
  else      acc[(size_t)n * OUT + o] += a;
}

// ---------------- mean + root linear + bias + relu6 -> bf16 ----------------
template <int OUT>
__global__ void finalize(const float* __restrict__ acc, const int* __restrict__ rows,
                         const u16* __restrict__ featA, const u16* __restrict__ featB,
                         int inA, int inB, const float* __restrict__ rootW,
                         const float* __restrict__ bias, u16* __restrict__ dst) {
  const int tid = threadIdx.x;
  const int NPB = 64 / OUT;
  const int n = blockIdx.x * NPB + tid / OUT;
  const int o = tid % OUT;
  const int d = rows[n + 1] - rows[n];
  float a = acc[(size_t)n * OUT + o] / fmaxf((float)d, 1.f);
  for (int i = 0; i < inA; ++i)
    a = fmaf(bf2f(featA[(size_t)n * inA + i]), rootW[i * OUT + o], a);
  for (int i = 0; i < inB; ++i)
    a = fmaf(bf2f(featB[(size_t)n * inB + i]), rootW[(inA + i) * OUT + o], a);
  a += bias[o];
  a = fmaxf(a, 0.f);
  a = fminf(a, 6.f);
  dst[(size_t)n * OUT + o] = f2bf(a);
}

// ---------------- final MLP ----------------
// h[g][j] = sum_t flat[g][t] * W1[t][j] ; 64x128x32768 GEMM, W1 read once.
// grid.x = 128 chunks of 256 t; block = 128 threads (j); acc[64 graphs]/thread.
__global__ void mlp1(const u16* __restrict__ d1, const float* __restrict__ w1,
                     float* __restrict__ hbuf) {
  __shared__ u16 fl[64 * 256];
  const int c0 = blockIdx.x * 256;
  const int j = threadIdx.x;
  for (int idx = j; idx < 8192; idx += 128) {       // 8192 u32 = 64g * 128
    int g = idx >> 7, p = idx & 127;
    ((u32*)fl)[idx] = ((const u32*)d1)[(size_t)g * 16384 + (c0 >> 1) + p];
  }
  __syncthreads();
  float acc[64];
#pragma unroll
  for (int g = 0; g < 64; ++g) acc[g] = 0.f;
  for (int t = 0; t < 256; ++t) {
    float w = w1[(size_t)(c0 + t) * 128 + j];
#pragma unroll
    for (int g = 0; g < 64; ++g)
      acc[g] = fmaf(bf2f(fl[g * 256 + t]), w, acc[g]);
  }
  for (int g = 0; g < 64; ++g)
    atomicAdd(&hbuf[g * 128 + j], acc[g]);
}

__global__ void mlp2(const float* __restrict__ hbuf, const float* __restrict__ b1,
                     const float* __restrict__ w2, const float* __restrict__ b2,
                     float* __restrict__ out) {
  const int t = threadIdx.x;
  if (t >= BB * 3) return;
  const int g = t / 3, c = t % 3;
  float acc = b2[c];
  for (int j = 0; j < 128; ++j) {
    float h = fmaxf(hbuf[g * 128 + j] + b1[j], 0.f);
    acc = fmaf(h, w2[j * 3 + c], acc);
  }
  out[g * 3 + c] = acc;
}

// ---------------- launch ----------------
extern "C" void kernel_launch(void* const* d_in, const int* in_sizes, int n_in,
                              void* d_out, int out_size, void* d_ws, size_t ws_size,
                              hipStream_t stream) {
  const float* x    = (const float*)d_in[0];
  const int*   ei   = (const int*)d_in[1];
  const float* pos  = (const float*)d_in[2];

  char* base = (char*)d_ws;
  u16*   xb     = (u16*)(base + O_XBF);
  float* coeff  = (float*)(base + O_COEFF);
  int*   deg    = (int*)(base + O_DEG);
  float* hbuf   = (float*)(base + O_HBUF);
  int*   rows   = (int*)(base + O_ROWS);
  int*   cursor = (int*)(base + O_CURS);
  int*   bsum   = (int*)(base + O_BSUM);
  int*   csr    = (int*)(base + O_CSR);
  u16*   h1     = (u16*)(base + O_H1);
  u16*   h2     = (u16*)(base + O_H2);
  u16*   h3     = (u16*)(base + O_H3);
  u16*   d0     = (u16*)(base + O_D0);
  u16*   d1     = (u16*)(base + O_D1);
  float* acc    = (float*)(base + O_ACC);
  u16*   xw     = (u16*)(base + O_XW);

  hipMemsetAsync(base + O_DEG, 0, 262144 + 32768, stream);  // deg + hbuf

  cvt_x<<<NN * 16 / 256, 256, 0, stream>>>(x, xb);
  edge_prep<<<EE / 256, 256, 0, stream>>>(pos, ei, coeff, deg);
  scan1<<<256, 256, 0, stream>>>(deg, rows, bsum);
  scan2<<<1, 256, 0, stream>>>(bsum);
  scan3<<<256, 256, 0, stream>>>(rows, bsum, cursor);
  edge_fill<<<EE / 256, 256, 0, stream>>>(ei, cursor, csr);

  struct L { const u16* fa; const u16* fb; int inA, inB, out;
             const float* W; const float* R; const float* Bb; u16* dst; };
  const L layers[5] = {
    { xb, nullptr, 16,  0, 32, (const float*)d_in[4],  (const float*)d_in[5],  (const float*)d_in[6],  h1 },
    { h1, nullptr, 32,  0, 64, (const float*)d_in[7],  (const float*)d_in[8],  (const float*)d_in[9],  h2 },
    { h2, nullptr, 64,  0, 64, (const float*)d_in[10], (const float*)d_in[11], (const float*)d_in[12], h3 },
    { h3, h2,      64, 64, 64, (const float*)d_in[13], (const float*)d_in[14], (const float*)d_in[15], d0 },
    { d0, h1,      64, 32, 32, (const float*)d_in[16], (const float*)d_in[17], (const float*)d_in[18], d1 },
  };
  for (int l = 0; l < 5; ++l) {
    const L& ly = layers[l];
    const int in = ly.inA + ly.inB;
    const int NODES = (256 / ly.out) * 4;
    size_t lds = ((size_t)in * ly.out + (size_t)NODES * in) * sizeof(float);
    for (int g = 0; g < 3; ++g) {
      dim3 grid(NN / NODES, 3);
      gemm_xw<<<grid, 256, lds, stream>>>(ly.fa, ly.fb, ly.inA, ly.inB,
                                          ly.W + (size_t)(3 * g) * in * ly.out,
                                          xw, ly.out);
      if (ly.out == 64) {
        if (g == 0) aggregate_g<64, true ><<<NN, 64, 0, stream>>>(xw, coeff, ei, csr, rows, 3 * g, acc);
        else        aggregate_g<64, false><<<NN, 64, 0, stream>>>(xw, coeff, ei, csr, rows, 3 * g, acc);
      } else {
        if (g == 0) aggregate_g<32, true ><<<NN / 2, 64, 0, stream>>>(xw, coeff, ei, csr, rows, 3 * g, acc);
        else        aggregate_g<32, false><<<NN / 2, 64, 0, stream>>>(xw, coeff, ei, csr, rows, 3 * g, acc);
      }
    }
    if (ly.out == 64)
      finalize<64><<<NN, 64, 0, stream>>>(acc, rows, ly.fa, ly.fb, ly.inA, ly.inB,
                                          ly.R, ly.Bb, ly.dst);
    else
      finalize<32><<<NN / 2, 64, 0, stream>>>(acc, rows, ly.fa, ly.fb, ly.inA, ly.inB,
                                              ly.R, ly.Bb, ly.dst);
  }

  mlp1<<<128, 128, 0, stream>>>(d1, (const float*)d_in[19], hbuf);
  mlp2<<<1, 256, 0, stream>>>(hbuf, (const float*)d_in[20], (const float*)d_in[21],
                              (const float*)d_in[22], (float*)d_out);
}

// Round 4
// 823.108 us; speedup vs baseline: 3.0959x; 3.0959x over previous
//
#include <hip/hip_runtime.h>

#define KS 3
#define NN 65536
#define EE 524288
#define BB 64

typedef unsigned short u16;
typedef unsigned int u32;

typedef __attribute__((ext_vector_type(8))) short bf16x8;
typedef __attribute__((ext_vector_type(4))) float f32x4;

__device__ __forceinline__ float bf2f(u16 u) {
  union { u32 i; float f; } v; v.i = ((u32)u) << 16; return v.f;
}
__device__ __forceinline__ u16 f2bf(float f) {
  union { float f; u32 i; } v; v.f = f;
  u32 x = v.i;
  x += 0x7fffu + ((x >> 16) & 1u);   // RNE
  return (u16)(x >> 16);
}

// ---------------- ws byte offsets (total 99,354,176 <= round-3-proven 99,386,624) ----------------
static const size_t O_CR   = 0;                    // coeff_csr: E rows x 5 u32 (src_u16 + 9 bf16 coeff/deg) = 10,485,760
static const size_t O_HBUF = 0;                    // 64*128 f32 overlays CR during MLP phase
static const size_t O_ROWS = 10485760;             // (N+1) i32, padded to 262,400
static const size_t O_BMAT = 10748160;             // packed B mats, 366,592 B (overlays cursor+deg after prep)
static const size_t O_CURS = 10748160;             // N i32
static const size_t O_DEG  = 11010304;             // N i32
static const size_t O_BSUM = 11272448;             // 256 i32 pad 1024
static const size_t O_H1   = 11273472;             // N*32 bf16
static const size_t O_H2   = 15467776;             // N*64 bf16
static const size_t O_H3   = 23856384;             // N*64 bf16
static const size_t O_D0   = 32244992;             // N*64 bf16
static const size_t O_D1   = 40633600;             // N*32 bf16 (end 44,827,904 + slack)
static const size_t O_AGG  = 44828160;             // N*288 bf16 = 37,748,736 (+64 slack)
static const size_t O_ACC  = 82576960;             // N*64 f32 = 16,777,216 -> end 99,354,176

// ---------------- prep: degree histogram ----------------
__global__ void hist_kernel(const int* __restrict__ ei, int* __restrict__ deg) {
  int e = blockIdx.x * 256 + threadIdx.x;
  int d = ei[EE + e]; d = min(max(d, 0), NN - 1);
  atomicAdd(&deg[d], 1);
}

// ---------------- scans over deg[N], N = 256*256 ----------------
__global__ void scan1(const int* __restrict__ deg, int* __restrict__ rows,
                      int* __restrict__ bsum) {
  __shared__ int s[256];
  int t = threadIdx.x, b = blockIdx.x, i = b * 256 + t;
  int v = deg[i];
  s[t] = v; __syncthreads();
  for (int off = 1; off < 256; off <<= 1) {
    int x = (t >= off) ? s[t - off] : 0; __syncthreads();
    s[t] += x; __syncthreads();
  }
  rows[i] = s[t] - v;
  if (t == 255) bsum[b] = s[255];
}
__global__ void scan2(int* __restrict__ bsum) {
  __shared__ int s[256];
  int t = threadIdx.x;
  int v = bsum[t];
  s[t] = v; __syncthreads();
  for (int off = 1; off < 256; off <<= 1) {
    int x = (t >= off) ? s[t - off] : 0; __syncthreads();
    s[t] += x; __syncthreads();
  }
  bsum[t] = s[t] - v;
}
__global__ void scan3(int* __restrict__ rows, const int* __restrict__ bsum,
                      int* __restrict__ cursor) {
  int t = threadIdx.x, b = blockIdx.x, i = b * 256 + t;
  int v = rows[i] + bsum[b];
  rows[i] = v;
  cursor[i] = v;
  if (i == NN - 1) rows[NN] = EE;
}

// ---------------- fill CSR rows: (src_u16, 9 x bf16(coeff/deg)) packed in 5 u32 ----------------
__global__ void fill_kernel(const int* __restrict__ ei, const float* __restrict__ pos,
                            const int* __restrict__ deg, int* __restrict__ cursor,
                            u32* __restrict__ cr) {
  int e = blockIdx.x * 256 + threadIdx.x;
  int src = ei[e];      src = min(max(src, 0), NN - 1);
  int dst = ei[EE + e]; dst = min(max(dst, 0), NN - 1);
  float2 p = ((const float2*)pos)[e];
  float fl0 = floorf(p.x), fl1 = floorf(p.y);
  float f0 = p.x - fl0, f1 = p.y - fl1;
  int b0 = (int)fl0, b1 = (int)fl1;
  float w0[3] = { 0.5f*(1.f-f0)*(1.f-f0), -f0*f0+f0+0.5f, 0.5f*f0*f0 };
  float w1[3] = { 0.5f*(1.f-f1)*(1.f-f1), -f1*f1+f1+0.5f, 0.5f*f1*f1 };
  int i0[3], i1[3];
#pragma unroll
  for (int s = 0; s < 3; ++s) {
    i0[s] = min(max(b0 + s, 0), KS - 1);
    i1[s] = min(max(b1 + s, 0), KS - 1);
  }
  float c[9] = {0,0,0,0,0,0,0,0,0};
#pragma unroll
  for (int s0 = 0; s0 < 3; ++s0)
#pragma unroll
    for (int s1 = 0; s1 < 3; ++s1)
      c[i0[s0] + KS * i1[s1]] += w0[s0] * w1[s1];
  float scale = 1.f / (float)max(deg[dst], 1);   // fold mean into coeffs
  u16 h[9];
#pragma unroll
  for (int k = 0; k < 9; ++k) h[k] = f2bf(c[k] * scale);
  int slot = atomicAdd(&cursor[dst], 1);
  slot = min(max(slot, 0), EE - 1);
  size_t b = (size_t)slot * 5;
  cr[b + 0] = (u32)(u16)src | ((u32)h[0] << 16);
  cr[b + 1] = (u32)h[1] | ((u32)h[2] << 16);
  cr[b + 2] = (u32)h[3] | ((u32)h[4] << 16);
  cr[b + 3] = (u32)h[5] | ((u32)h[6] << 16);
  cr[b + 4] = (u32)h[7] | ((u32)h[8] << 16);
}

// ---------------- build packed B matrices (MFMA B-fragment order: [o][k] k-contig) ----------------
struct BDesc { const float* W; int dstOff, i0, INW, OUT, K, isRoot; };
struct BDescs { BDesc d[17]; };

__global__ void build_b(BDescs ds, u16* __restrict__ bmat) {
  BDesc d = ds.d[blockIdx.y];
  int idx = blockIdx.x * 256 + threadIdx.x;
  int elems = d.K * d.OUT;
  if (idx >= elems) return;
  int o = idx / d.K, r = idx - o * d.K;
  float v;
  if (d.isRoot) {
    v = d.W[(size_t)(d.i0 + r) * d.OUT + o];
  } else {
    int kk = r >> 5, ii = r & 31;
    int i = d.i0 + ii;
    v = (i < d.INW) ? d.W[((size_t)kk * d.INW + i) * d.OUT + o] : 0.f;
  }
  bmat[(size_t)d.dstOff + (size_t)o * d.K + r] = f2bf(v);
}

// ---------------- scatter pass: agg[n, k, i] = sum_e (c_ek/deg) * x[src_e, i0+i] ----------------
__global__ __launch_bounds__(256) void scatter(const u16* __restrict__ srcB,
                                               const float* __restrict__ srcF, int useF,
                                               int srcIN, int i0src,
                                               const u32* __restrict__ cr,
                                               const int* __restrict__ rows,
                                               u16* __restrict__ agg) {
  const int tid = threadIdx.x;
  const int n = blockIdx.x * 4 + (tid >> 6);
  const int lane = tid & 63;
  const int l = lane & 31, half = lane >> 5;
  const int rs = rows[n], re = rows[n + 1];
  const int i = i0src + l;
  const bool valid = i < srcIN;
  float a[9];
#pragma unroll
  for (int k = 0; k < 9; ++k) a[k] = 0.f;
  for (int r = rs + half; r < re; r += 2) {
    const u32* w = cr + (size_t)r * 5;
    u32 w0 = w[0], w1 = w[1], w2 = w[2], w3 = w[3], w4 = w[4];
    int s = (int)(w0 & 0xffffu);
    float xv = 0.f;
    if (valid) xv = useF ? srcF[(size_t)s * srcIN + i]
                         : bf2f(srcB[(size_t)s * srcIN + i]);
    a[0] = fmaf(bf2f((u16)(w0 >> 16)), xv, a[0]);
    a[1] = fmaf(bf2f((u16)(w1 & 0xffffu)), xv, a[1]);
    a[2] = fmaf(bf2f((u16)(w1 >> 16)), xv, a[2]);
    a[3] = fmaf(bf2f((u16)(w2 & 0xffffu)), xv, a[3]);
    a[4] = fmaf(bf2f((u16)(w2 >> 16)), xv, a[4]);
    a[5] = fmaf(bf2f((u16)(w3 & 0xffffu)), xv, a[5]);
    a[6] = fmaf(bf2f((u16)(w3 >> 16)), xv, a[6]);
    a[7] = fmaf(bf2f((u16)(w4 & 0xffffu)), xv, a[7]);
    a[8] = fmaf(bf2f((u16)(w4 >> 16)), xv, a[8]);
  }
#pragma unroll
  for (int k = 0; k < 9; ++k) a[k] += __shfl_xor(a[k], 32);
  if (half == 0) {
#pragma unroll
    for (int k = 0; k < 9; ++k)
      agg[(size_t)n * 288 + k * 32 + l] = f2bf(a[k]);
  }
}

// ---------------- MFMA GEMM pass: acc[n, o] (+)= A[n, :] @ Bp ----------------
// MODE 0 = init store, 1 = accumulate, 2 = final (+bias, relu6, bf16 store)
template <int OUT, int MODE>
__global__ __launch_bounds__(256) void gemm_pass(const u16* __restrict__ A, int astride,
                                                 int ksteps, const u16* __restrict__ Bp,
                                                 float* __restrict__ acc,
                                                 const float* __restrict__ bias,
                                                 u16* __restrict__ dst) {
  constexpr int NT = OUT / 16;
  const int tid = threadIdx.x;
  const int wave = tid >> 6, lane = tid & 63;
  const int quad = lane >> 4, l16 = lane & 15;
  const int m0 = blockIdx.x * 256 + wave * 64;
  f32x4 C[4][NT];
#pragma unroll
  for (int mt = 0; mt < 4; ++mt)
#pragma unroll
    for (int nt = 0; nt < NT; ++nt) C[mt][nt] = (f32x4){0.f, 0.f, 0.f, 0.f};

  for (int ks = 0; ks < ksteps; ++ks) {
    bf16x8 bf[NT];
#pragma unroll
    for (int nt = 0; nt < NT; ++nt)
      bf[nt] = *(const bf16x8*)(Bp + ((size_t)(nt * 16 + l16) * ksteps + ks) * 32 + quad * 8);
    bf16x8 av[4];
#pragma unroll
    for (int mt = 0; mt < 4; ++mt)
      av[mt] = *(const bf16x8*)(A + (size_t)(m0 + mt * 16 + l16) * astride + ks * 32 + quad * 8);
#pragma unroll
    for (int mt = 0; mt < 4; ++mt)
#pragma unroll
      for (int nt = 0; nt < NT; ++nt)
        C[mt][nt] = __builtin_amdgcn_mfma_f32_16x16x32_bf16(av[mt], bf[nt], C[mt][nt], 0, 0, 0);
  }
#pragma unroll
  for (int mt = 0; mt < 4; ++mt)
#pragma unroll
    for (int nt = 0; nt < NT; ++nt)
#pragma unroll
      for (int r = 0; r < 4; ++r) {
        int node = m0 + mt * 16 + quad * 4 + r;     // C/D: row = quad*4+reg (m89)
        int o = nt * 16 + l16;                       //      col = lane&15
        size_t idx = (size_t)node * OUT + o;
        float v = C[mt][nt][r];
        if (MODE == 0) acc[idx] = v;
        else if (MODE == 1) acc[idx] += v;
        else {
          v += acc[idx] + bias[o];
          v = fminf(fmaxf(v, 0.f), 6.f);
          dst[idx] = f2bf(v);
        }
      }
}

// ---------------- enc0 root (in=16, fp32 x) + bias + relu6 ----------------
__global__ void root_enc0(const float* __restrict__ x, const float* __restrict__ R,
                          const float* __restrict__ b, const float* __restrict__ acc,
                          u16* __restrict__ h1) {
  const int tid = threadIdx.x;
  const int n = blockIdx.x * 8 + (tid >> 5);
  const int o = tid & 31;
  float a = acc[(size_t)n * 32 + o] + b[o];
#pragma unroll
  for (int i = 0; i < 16; ++i)
    a = fmaf(x[(size_t)n * 16 + i], R[i * 32 + o], a);
  a = fminf(fmaxf(a, 0.f), 6.f);
  h1[(size_t)n * 32 + o] = f2bf(a);
}

// ---------------- final MLP: C[64,128] = d1_flat[64,32768] @ W1, MFMA split-K ----------------
__global__ __launch_bounds__(256) void mlp1(const u16* __restrict__ d1,
                                            const float* __restrict__ w1,
                                            float* __restrict__ hbuf) {
  __shared__ __align__(16) u16 bt[128 * 136];   // Bt[col][k], stride 136 (16B align, 2-way banks)
  const int tid = threadIdx.x;
  const int c0 = blockIdx.x * 128;
  for (int idx = tid; idx < 16384; idx += 256) {
    int k = idx >> 7, col = idx & 127;
    bt[col * 136 + k] = f2bf(w1[(size_t)(c0 + k) * 128 + col]);
  }
  __syncthreads();
  const int wave = tid >> 6, lane = tid & 63;
  const int quad = lane >> 4, l16 = lane & 15;
  f32x4 C[8];
#pragma unroll
  for (int nt = 0; nt < 8; ++nt) C[nt] = (f32x4){0.f, 0.f, 0.f, 0.f};
  for (int ks = 0; ks < 4; ++ks) {
    bf16x8 av = *(const bf16x8*)(d1 + (size_t)(wave * 16 + l16) * 32768 + c0 + ks * 32 + quad * 8);
#pragma unroll
    for (int nt = 0; nt < 8; ++nt) {
      bf16x8 bv = *(const bf16x8*)&bt[(nt * 16 + l16) * 136 + ks * 32 + quad * 8];
      C[nt] = __builtin_amdgcn_mfma_f32_16x16x32_bf16(av, bv, C[nt], 0, 0, 0);
    }
  }
#pragma unroll
  for (int nt = 0; nt < 8; ++nt)
#pragma unroll
    for (int r = 0; r < 4; ++r) {
      int g = wave * 16 + quad * 4 + r;
      int o = nt * 16 + l16;
      atomicAdd(&hbuf[g * 128 + o], C[nt][r]);
    }
}

__global__ void mlp2(const float* __restrict__ hbuf, const float* __restrict__ b1,
                     const float* __restrict__ w2, const float* __restrict__ b2,
                     float* __restrict__ out) {
  const int t = threadIdx.x;
  if (t >= BB * 3) return;
  const int g = t / 3, c = t % 3;
  float acc = b2[c];
  for (int j = 0; j < 128; ++j) {
    float h = fmaxf(hbuf[g * 128 + j] + b1[j], 0.f);
    acc = fmaf(h, w2[j * 3 + c], acc);
  }
  out[g * 3 + c] = acc;
}

// ---------------- launch ----------------
extern "C" void kernel_launch(void* const* d_in, const int* in_sizes, int n_in,
                              void* d_out, int out_size, void* d_ws, size_t ws_size,
                              hipStream_t stream) {
  const float* x   = (const float*)d_in[0];
  const int*   ei  = (const int*)d_in[1];
  const float* pos = (const float*)d_in[2];

  char* base = (char*)d_ws;
  u32*   cr     = (u32*)(base + O_CR);
  float* hbuf   = (float*)(base + O_HBUF);
  int*   rows   = (int*)(base + O_ROWS);
  u16*   bmat   = (u16*)(base + O_BMAT);
  int*   cursor = (int*)(base + O_CURS);
  int*   deg    = (int*)(base + O_DEG);
  int*   bsum   = (int*)(base + O_BSUM);
  u16*   h1     = (u16*)(base + O_H1);
  u16*   h2     = (u16*)(base + O_H2);
  u16*   h3     = (u16*)(base + O_H3);
  u16*   d0     = (u16*)(base + O_D0);
  u16*   d1     = (u16*)(base + O_D1);
  u16*   agg    = (u16*)(base + O_AGG);
  float* acc    = (float*)(base + O_ACC);

  hipMemsetAsync(deg, 0, 262144, stream);

  hist_kernel<<<EE / 256, 256, 0, stream>>>(ei, deg);
  scan1<<<256, 256, 0, stream>>>(deg, rows, bsum);
  scan2<<<1, 256, 0, stream>>>(bsum);
  scan3<<<256, 256, 0, stream>>>(rows, bsum, cursor);
  fill_kernel<<<EE / 256, 256, 0, stream>>>(ei, pos, deg, cursor, cr);

  // packed-B descriptors (dstOff in u16 units)
  const float* W_e0 = (const float*)d_in[4];
  const float* R_e0 = (const float*)d_in[5];
  const float* B_e0 = (const float*)d_in[6];
  const float* W_e1 = (const float*)d_in[7];
  const float* R_e1 = (const float*)d_in[8];
  const float* B_e1 = (const float*)d_in[9];
  const float* W_e2 = (const float*)d_in[10];
  const float* R_e2 = (const float*)d_in[11];
  const float* B_e2 = (const float*)d_in[12];
  const float* W_d0 = (const float*)d_in[13];
  const float* R_d0 = (const float*)d_in[14];
  const float* B_d0 = (const float*)d_in[15];
  const float* W_d1 = (const float*)d_in[16];
  const float* R_d1 = (const float*)d_in[17];
  const float* B_d1 = (const float*)d_in[18];

  BDescs ds;
  // chunk passes: {W, dstOff, i0(chunk base in concat-in), INW, OUT, K=288, 0}
  ds.d[0]  = { W_e0, 0,      0,  16,  32, 288, 0 };
  ds.d[1]  = { W_e1, 9216,   0,  32,  64, 288, 0 };
  ds.d[2]  = { W_e2, 27648,  0,  64,  64, 288, 0 };
  ds.d[3]  = { W_e2, 46080,  32, 64,  64, 288, 0 };
  ds.d[4]  = { W_d0, 64512,  0,  128, 64, 288, 0 };
  ds.d[5]  = { W_d0, 82944,  32, 128, 64, 288, 0 };
  ds.d[6]  = { W_d0, 101376, 64, 128, 64, 288, 0 };
  ds.d[7]  = { W_d0, 119808, 96, 128, 64, 288, 0 };
  ds.d[8]  = { W_d1, 138240, 0,  96,  32, 288, 0 };
  ds.d[9]  = { W_d1, 147456, 32, 96,  32, 288, 0 };
  ds.d[10] = { W_d1, 156672, 64, 96,  32, 288, 0 };
  // root passes: {R, dstOff, i0(row base in R), -, OUT, K, 1}
  ds.d[11] = { R_e1, 165888, 0,  0, 64, 32, 1 };
  ds.d[12] = { R_e2, 167936, 0,  0, 64, 64, 1 };
  ds.d[13] = { R_d0, 172032, 0,  0, 64, 64, 1 };
  ds.d[14] = { R_d0, 176128, 64, 0, 64, 64, 1 };
  ds.d[15] = { R_d1, 180224, 0,  0, 32, 64, 1 };
  ds.d[16] = { R_d1, 182272, 64, 0, 32, 32, 1 };
  build_b<<<dim3(72, 17), 256, 0, stream>>>(ds, bmat);

  const int SG = NN / 4;    // scatter grid
  const int GG = NN / 256;  // gemm grid

  // ---- enc0: in=16 (x, f32), out=32 ----
  scatter<<<SG, 256, 0, stream>>>(nullptr, x, 1, 16, 0, cr, rows, agg);
  gemm_pass<32, 0><<<GG, 256, 0, stream>>>(agg, 288, 9, bmat + 0, acc, nullptr, nullptr);
  root_enc0<<<NN / 8, 256, 0, stream>>>(x, R_e0, B_e0, acc, h1);

  // ---- enc1: in=32 (h1), out=64 ----
  scatter<<<SG, 256, 0, stream>>>(h1, nullptr, 0, 32, 0, cr, rows, agg);
  gemm_pass<64, 0><<<GG, 256, 0, stream>>>(agg, 288, 9, bmat + 9216, acc, nullptr, nullptr);
  gemm_pass<64, 2><<<GG, 256, 0, stream>>>(h1, 32, 1, bmat + 165888, acc, B_e1, h2);

  // ---- enc2: in=64 (h2), out=64 ----
  scatter<<<SG, 256, 0, stream>>>(h2, nullptr, 0, 64, 0, cr, rows, agg);
  gemm_pass<64, 0><<<GG, 256, 0, stream>>>(agg, 288, 9, bmat + 27648, acc, nullptr, nullptr);
  scatter<<<SG, 256, 0, stream>>>(h2, nullptr, 0, 64, 32, cr, rows, agg);
  gemm_pass<64, 1><<<GG, 256, 0, stream>>>(agg, 288, 9, bmat + 46080, acc, nullptr, nullptr);
  gemm_pass<64, 2><<<GG, 256, 0, stream>>>(h2, 64, 2, bmat + 167936, acc, B_e2, h3);

  // ---- dec0: in=concat(h3:64, h2:64)=128, out=64 ----
  scatter<<<SG, 256, 0, stream>>>(h3, nullptr, 0, 64, 0, cr, rows, agg);
  gemm_pass<64, 0><<<GG, 256, 0, stream>>>(agg, 288, 9, bmat + 64512, acc, nullptr, nullptr);
  scatter<<<SG, 256, 0, stream>>>(h3, nullptr, 0, 64, 32, cr, rows, agg);
  gemm_pass<64, 1><<<GG, 256, 0, stream>>>(agg, 288, 9, bmat + 82944, acc, nullptr, nullptr);
  scatter<<<SG, 256, 0, stream>>>(h2, nullptr, 0, 64, 0, cr, rows, agg);
  gemm_pass<64, 1><<<GG, 256, 0, stream>>>(agg, 288, 9, bmat + 101376, acc, nullptr, nullptr);
  scatter<<<SG, 256, 0, stream>>>(h2, nullptr, 0, 64, 32, cr, rows, agg);
  gemm_pass<64, 1><<<GG, 256, 0, stream>>>(agg, 288, 9, bmat + 119808, acc, nullptr, nullptr);
  gemm_pass<64, 1><<<GG, 256, 0, stream>>>(h3, 64, 2, bmat + 172032, acc, nullptr, nullptr);
  gemm_pass<64, 2><<<GG, 256, 0, stream>>>(h2, 64, 2, bmat + 176128, acc, B_d0, d0);

  // ---- dec1: in=concat(d0:64, h1:32)=96, out=32 ----
  scatter<<<SG, 256, 0, stream>>>(d0, nullptr, 0, 64, 0, cr, rows, agg);
  gemm_pass<32, 0><<<GG, 256, 0, stream>>>(agg, 288, 9, bmat + 138240, acc, nullptr, nullptr);
  scatter<<<SG, 256, 0, stream>>>(d0, nullptr, 0, 64, 32, cr, rows, agg);
  gemm_pass<32, 1><<<GG, 256, 0, stream>>>(agg, 288, 9, bmat + 147456, acc, nullptr, nullptr);
  scatter<<<SG, 256, 0, stream>>>(h1, nullptr, 0, 32, 0, cr, rows, agg);
  gemm_pass<32, 1><<<GG, 256, 0, stream>>>(agg, 288, 9, bmat + 156672, acc, nullptr, nullptr);
  gemm_pass<32, 1><<<GG, 256, 0, stream>>>(d0, 64, 2, bmat + 180224, acc, nullptr, nullptr);
  gemm_pass<32, 2><<<GG, 256, 0, stream>>>(h1, 32, 1, bmat + 182272, acc, B_d1, d1);

  // ---- final MLP ----
  hipMemsetAsync(hbuf, 0, 32768, stream);   // overlays cr (dead now)
  mlp1<<<256, 256, 0, stream>>>(d1, (const float*)d_in[19], hbuf);
  mlp2<<<1, 256, 0, stream>>>(hbuf, (const float*)d_in[20], (const float*)d_in[21],
                              (const float*)d_in[22], (float*)d_out);
}